// Round 1
// baseline (26505.911 us; speedup 1.0000x reference)
//
#include <hip/hip_runtime.h>
#include <hip/hip_bf16.h>

#define B_   64
#define T_   2048
#define F_   256
#define H_   512
#define NWG  64

typedef __attribute__((ext_vector_type(8))) short bfrag;   // 8 bf16 = 4 VGPR (MFMA A/B operand)
typedef __attribute__((ext_vector_type(4))) short short4_t;
typedef __attribute__((ext_vector_type(4))) float f32x4;   // MFMA C/D
typedef __attribute__((ext_vector_type(4))) float float4_t;

__device__ __forceinline__ float fsig(float x)  { return 1.0f / (1.0f + __expf(-x)); }
__device__ __forceinline__ float ftanh(float x) { return 2.0f / (1.0f + __expf(-2.0f * x)) - 1.0f; }

__device__ __forceinline__ short f2bf(float f) {
  __hip_bfloat16 h = __float2bfloat16(f);
  return __builtin_bit_cast(short, h);
}

// ---------------- init: zero flags, h0 = bf16(z) ----------------
__global__ void lstm_init(const float* __restrict__ z, __hip_bfloat16* __restrict__ hb0,
                          int* __restrict__ wgdone) {
  int i = blockIdx.x * blockDim.x + threadIdx.x;
  if (i < NWG) wgdone[i] = 0;
  for (int idx = i; idx < B_ * H_; idx += gridDim.x * blockDim.x)
    hb0[idx] = __float2bfloat16(z[idx]);
}

// ---------------- persistent LSTM ----------------
// WG g owns: gate rows {q*512 + g*8 + j : q=0..3, j=0..7}  -> h cols [g*8, g*8+8)
//            out cols  [g*4, g*4+4)
// Wave w handles batch rows [16w, 16w+16).
// MFMA 16x16x32 bf16 layouts (m89/m97-verified):
//   A[m][k]: m = lane%16, k = (lane/16)*8 + e
//   B[k][n]: n = lane%16, k = (lane/16)*8 + e   (loaded from row-major W[n][k])
//   D[m][n]: n = lane%16, m = 4*(lane/16) + reg
__global__ void __launch_bounds__(256, 1)
lstm_persist(const float* __restrict__ x,
             const float* __restrict__ Wih,  const float* __restrict__ Whh,
             const float* __restrict__ bih,  const float* __restrict__ bhh,
             const float* __restrict__ Wlin, const float* __restrict__ blin,
             float* __restrict__ out,
             __hip_bfloat16* __restrict__ hb0, __hip_bfloat16* __restrict__ hb1,
             int* __restrict__ wgdone)
{
  const int g   = blockIdx.x;        // 0..63
  const int tid = threadIdx.x;
  const int wv  = tid >> 6;          // wave 0..3
  const int l   = tid & 63;
  const int l16 = l & 15;
  const int lk  = (l >> 4) << 3;     // k sub-offset: 0,8,16,24

  // ---- persistent weight fragments in VGPRs (bf16) ----
  bfrag BW[2][24];   // [n-tile][k-tile]; k-tiles 0..7 from W_ih (K 0..255), 8..23 from W_hh
  #pragma unroll
  for (int nt = 0; nt < 2; ++nt) {
    const int n   = nt * 16 + l16;
    const int row = (n >> 3) * H_ + g * 8 + (n & 7);   // gate row
    #pragma unroll
    for (int kt = 0; kt < 24; ++kt) {
      const float* src = (kt < 8) ? (Wih + (size_t)row * F_ + kt * 32 + lk)
                                  : (Whh + (size_t)row * H_ + (kt - 8) * 32 + lk);
      bfrag w;
      #pragma unroll
      for (int e = 0; e < 8; ++e) w[e] = f2bf(src[e]);
      BW[nt][kt] = w;
    }
  }
  bfrag BL[16];      // W_lin fragments (cols g*4 .. g*4+3 valid; others zeroed)
  {
    const bool v  = (l16 < 4);
    const int col = g * 4 + (l16 & 3);   // clamped in-bounds for all lanes
    #pragma unroll
    for (int kt = 0; kt < 16; ++kt) {
      bfrag w;
      #pragma unroll
      for (int e = 0; e < 8; ++e)
        w[e] = v ? f2bf(Wlin[(size_t)col * H_ + kt * 32 + lk + e]) : (short)0;
      BL[kt] = w;
    }
  }
  float bs0 = 0.f, bs1 = 0.f, bs2 = 0.f, bs3 = 0.f, blc = 0.f;
  if (l16 < 8) {
    const int c0 = g * 8 + l16;
    bs0 = bih[c0]          + bhh[c0];           // i
    bs1 = bih[H_ + c0]     + bhh[H_ + c0];      // f
    bs2 = bih[2 * H_ + c0] + bhh[2 * H_ + c0];  // g
    bs3 = bih[3 * H_ + c0] + bhh[3 * H_ + c0];  // o
  }
  if (l16 < 4) blc = blin[g * 4 + l16];

  float c4[4] = {0.f, 0.f, 0.f, 0.f};           // cell state, rows dmBase+r

  const int am     = wv * 16 + l16;              // A-operand batch row
  const int dmBase = wv * 16 + ((l >> 4) << 2);  // D row base (+reg)

  for (int t = 0; t < T_; ++t) {
    // ---- wait for h_t ----
    if (t > 0) {
      if (tid < 64) {
        while (true) {
          int v = __hip_atomic_load(&wgdone[tid], __ATOMIC_RELAXED, __HIP_MEMORY_SCOPE_AGENT);
          if (__all(v >= t)) break;
          __builtin_amdgcn_s_sleep(1);
        }
        __builtin_amdgcn_fence(__ATOMIC_ACQUIRE, "agent");
      }
      __syncthreads();
    }

    const __hip_bfloat16* hcur = (t & 1) ? hb1 : hb0;
    __hip_bfloat16*       hnxt = (t & 1) ? hb0 : hb1;

    f32x4 acc0 = {0.f, 0.f, 0.f, 0.f};
    f32x4 acc1 = {0.f, 0.f, 0.f, 0.f};
    f32x4 oacc = {blc, blc, blc, blc};

    // ---- x part of gates GEMM (K 0..255), fp32 -> bf16 on the fly ----
    const float* xrow = x + ((size_t)am * T_ + t) * F_ + lk;
    #pragma unroll
    for (int kt = 0; kt < 8; ++kt) {
      float4_t xa = *(const float4_t*)(xrow + kt * 32);
      float4_t xb = *(const float4_t*)(xrow + kt * 32 + 4);
      bfrag a;
      #pragma unroll
      for (int e = 0; e < 4; ++e) { a[e] = f2bf(xa[e]); a[4 + e] = f2bf(xb[e]); }
      acc0 = __builtin_amdgcn_mfma_f32_16x16x32_bf16(a, BW[0][kt], acc0, 0, 0, 0);
      acc1 = __builtin_amdgcn_mfma_f32_16x16x32_bf16(a, BW[1][kt], acc1, 0, 0, 0);
    }
    // ---- h part (K 256..767) + out GEMM for step t-1 (reuses h frags) ----
    const unsigned long long* hrow =
        (const unsigned long long*)(hcur + (size_t)am * H_) + (lk >> 2);
    #pragma unroll
    for (int kt = 0; kt < 16; ++kt) {
      unsigned long long u0 = __hip_atomic_load(hrow + kt * 8,     __ATOMIC_RELAXED, __HIP_MEMORY_SCOPE_AGENT);
      unsigned long long u1 = __hip_atomic_load(hrow + kt * 8 + 1, __ATOMIC_RELAXED, __HIP_MEMORY_SCOPE_AGENT);
      short4_t s0 = __builtin_bit_cast(short4_t, u0);
      short4_t s1 = __builtin_bit_cast(short4_t, u1);
      bfrag a = __builtin_shufflevector(s0, s1, 0, 1, 2, 3, 4, 5, 6, 7);
      acc0 = __builtin_amdgcn_mfma_f32_16x16x32_bf16(a, BW[0][8 + kt], acc0, 0, 0, 0);
      acc1 = __builtin_amdgcn_mfma_f32_16x16x32_bf16(a, BW[1][8 + kt], acc1, 0, 0, 0);
      oacc = __builtin_amdgcn_mfma_f32_16x16x32_bf16(a, BL[kt],       oacc, 0, 0, 0);
    }

    // ---- activations, state update, h store, out store ----
    unsigned short* hst = (unsigned short*)hnxt;
    #pragma unroll
    for (int r = 0; r < 4; ++r) {
      float fvx = __shfl_xor(acc0[r], 8);   // f gate (n = 8+j) from partner lane
      float ovx = __shfl_xor(acc1[r], 8);   // o gate (n = 24+j)
      if (l16 < 8) {
        float iv = fsig(acc0[r] + bs0);
        float fv = fsig(fvx + bs1);
        float gv = ftanh(acc1[r] + bs2);
        float ov = fsig(ovx + bs3);
        float cn = fv * c4[r] + iv * gv;
        c4[r] = cn;
        float hn = ov * ftanh(cn);
        __hip_atomic_store(&hst[(size_t)(dmBase + r) * H_ + g * 8 + l16],
                           (unsigned short)f2bf(hn),
                           __ATOMIC_RELAXED, __HIP_MEMORY_SCOPE_AGENT);
      }
      if (t > 0 && l16 < 4) {
        out[(size_t)(dmBase + r) * T_ * F_ + (size_t)(t - 1) * F_ + g * 4 + l16] = oacc[r];
      }
    }

    __syncthreads();   // drains vmcnt(0): all waves' h stores at coherence point
    if (tid == 0)
      __hip_atomic_store(&wgdone[g], t + 1, __ATOMIC_RELEASE, __HIP_MEMORY_SCOPE_AGENT);
  }

  // ---- tail: out[:, T-1, :] from h_T (in hb0, since T even) ----
  if (tid < 64) {
    while (true) {
      int v = __hip_atomic_load(&wgdone[tid], __ATOMIC_RELAXED, __HIP_MEMORY_SCOPE_AGENT);
      if (__all(v >= T_)) break;
      __builtin_amdgcn_s_sleep(1);
    }
    __builtin_amdgcn_fence(__ATOMIC_ACQUIRE, "agent");
  }
  __syncthreads();
  {
    f32x4 oacc = {blc, blc, blc, blc};
    const unsigned long long* hrow =
        (const unsigned long long*)(hb0 + (size_t)am * H_) + (lk >> 2);
    #pragma unroll
    for (int kt = 0; kt < 16; ++kt) {
      unsigned long long u0 = __hip_atomic_load(hrow + kt * 8,     __ATOMIC_RELAXED, __HIP_MEMORY_SCOPE_AGENT);
      unsigned long long u1 = __hip_atomic_load(hrow + kt * 8 + 1, __ATOMIC_RELAXED, __HIP_MEMORY_SCOPE_AGENT);
      short4_t s0 = __builtin_bit_cast(short4_t, u0);
      short4_t s1 = __builtin_bit_cast(short4_t, u1);
      bfrag a = __builtin_shufflevector(s0, s1, 0, 1, 2, 3, 4, 5, 6, 7);
      oacc = __builtin_amdgcn_mfma_f32_16x16x32_bf16(a, BL[kt], oacc, 0, 0, 0);
    }
    if (l16 < 4) {
      #pragma unroll
      for (int r = 0; r < 4; ++r)
        out[(size_t)(dmBase + r) * T_ * F_ + (size_t)(T_ - 1) * F_ + g * 4 + l16] = oacc[r];
    }
  }
}

extern "C" void kernel_launch(void* const* d_in, const int* in_sizes, int n_in,
                              void* d_out, int out_size, void* d_ws, size_t ws_size,
                              hipStream_t stream) {
  const float* z    = (const float*)d_in[0];
  const float* x    = (const float*)d_in[1];
  const float* Wih  = (const float*)d_in[2];
  const float* Whh  = (const float*)d_in[3];
  const float* bih  = (const float*)d_in[4];
  const float* bhh  = (const float*)d_in[5];
  const float* Wlin = (const float*)d_in[6];
  const float* blin = (const float*)d_in[7];
  float* out = (float*)d_out;

  __hip_bfloat16* hb0 = (__hip_bfloat16*)d_ws;
  __hip_bfloat16* hb1 = hb0 + B_ * H_;
  int* wgdone = (int*)((char*)d_ws + (size_t)2 * B_ * H_ * sizeof(__hip_bfloat16));

  lstm_init<<<64, 256, 0, stream>>>(z, hb0, wgdone);
  lstm_persist<<<NWG, 256, 0, stream>>>(x, Wih, Whh, bih, bhh, Wlin, blin, out,
                                        hb0, hb1, wgdone);
}

// Round 2
// 18580.688 us; speedup vs baseline: 1.4265x; 1.4265x over previous
//
#include <hip/hip_runtime.h>
#include <hip/hip_bf16.h>

#define B_   64
#define T_   2048
#define F_   256
#define H_   512
#define NWG  64

typedef __attribute__((ext_vector_type(8))) short bfrag;   // 8 bf16 = 4 VGPR (MFMA A/B operand)
typedef __attribute__((ext_vector_type(4))) short short4_t;
typedef __attribute__((ext_vector_type(4))) float f32x4;   // MFMA C/D
typedef __attribute__((ext_vector_type(4))) float float4_t;

__device__ __forceinline__ float fsig(float x)  { return 1.0f / (1.0f + __expf(-x)); }
__device__ __forceinline__ float ftanh(float x) { return 2.0f / (1.0f + __expf(-2.0f * x)) - 1.0f; }

__device__ __forceinline__ short f2bf(float f) {
  __hip_bfloat16 h = __float2bfloat16(f);
  return __builtin_bit_cast(short, h);
}

// ---------------- init: zero flags, h0 = bf16(z) ----------------
__global__ void lstm_init(const float* __restrict__ z, __hip_bfloat16* __restrict__ hb0,
                          int* __restrict__ wgdone) {
  int i = blockIdx.x * blockDim.x + threadIdx.x;
  if (i < NWG) wgdone[i] = 0;
  for (int idx = i; idx < B_ * H_; idx += gridDim.x * blockDim.x)
    hb0[idx] = __float2bfloat16(z[idx]);
}

// ---------------- persistent LSTM ----------------
// WG g owns: gate rows {q*512 + g*8 + j : q=0..3, j=0..7}  -> h cols [g*8, g*8+8)
//            out cols  [g*4, g*4+4)
// Wave w handles batch rows [16w, 16w+16).
// Sync protocol: h + flags accessed ONLY via agent-scope relaxed atomics
// (bypass non-coherent L1/L2, serviced at coherence point). __syncthreads()
// drains vmcnt(0) [HIP-compiler] so h-stores have COMPLETED before the flag
// store issues -> no agent release/acquire fences (no L2 writeback/inv).
__global__ void __launch_bounds__(256, 1)
lstm_persist(const float* __restrict__ x,
             const float* __restrict__ Wih,  const float* __restrict__ Whh,
             const float* __restrict__ bih,  const float* __restrict__ bhh,
             const float* __restrict__ Wlin, const float* __restrict__ blin,
             float* __restrict__ out,
             __hip_bfloat16* __restrict__ hb0, __hip_bfloat16* __restrict__ hb1,
             int* __restrict__ wgdone)
{
  const int g   = blockIdx.x;        // 0..63
  const int tid = threadIdx.x;
  const int wv  = tid >> 6;          // wave 0..3
  const int l   = tid & 63;
  const int l16 = l & 15;
  const int lk  = (l >> 4) << 3;     // k sub-offset: 0,8,16,24

  // ---- persistent weight fragments in VGPRs/AGPRs (bf16) ----
  bfrag BW[2][24];   // [n-tile][k-tile]; k 0..7 = W_ih (K 0..255), 8..23 = W_hh
  #pragma unroll
  for (int nt = 0; nt < 2; ++nt) {
    const int n   = nt * 16 + l16;
    const int row = (n >> 3) * H_ + g * 8 + (n & 7);   // gate row
    #pragma unroll
    for (int kt = 0; kt < 24; ++kt) {
      const float* src = (kt < 8) ? (Wih + (size_t)row * F_ + kt * 32 + lk)
                                  : (Whh + (size_t)row * H_ + (kt - 8) * 32 + lk);
      bfrag w;
      #pragma unroll
      for (int e = 0; e < 8; ++e) w[e] = f2bf(src[e]);
      BW[nt][kt] = w;
    }
  }
  bfrag BL[16];      // W_lin fragments (cols g*4 .. g*4+3 valid; others zeroed)
  {
    const bool v  = (l16 < 4);
    const int col = g * 4 + (l16 & 3);
    #pragma unroll
    for (int kt = 0; kt < 16; ++kt) {
      bfrag w;
      #pragma unroll
      for (int e = 0; e < 8; ++e)
        w[e] = v ? f2bf(Wlin[(size_t)col * H_ + kt * 32 + lk + e]) : (short)0;
      BL[kt] = w;
    }
  }
  float bs0 = 0.f, bs1 = 0.f, bs2 = 0.f, bs3 = 0.f, blc = 0.f;
  if (l16 < 8) {
    const int c0 = g * 8 + l16;
    bs0 = bih[c0]          + bhh[c0];           // i
    bs1 = bih[H_ + c0]     + bhh[H_ + c0];      // f
    bs2 = bih[2 * H_ + c0] + bhh[2 * H_ + c0];  // g
    bs3 = bih[3 * H_ + c0] + bhh[3 * H_ + c0];  // o
  }
  if (l16 < 4) blc = blin[g * 4 + l16];

  float c4[4] = {0.f, 0.f, 0.f, 0.f};           // cell state, rows dmBase+r

  const int am     = wv * 16 + l16;              // A-operand batch row
  const int dmBase = wv * 16 + ((l >> 4) << 2);  // D row base (+reg)

  // x-part of the gates GEMM for step t (h-independent; runs in shadow phase)
  auto xpart = [&](int t, f32x4& a0, f32x4& a1) {
    const float* xrow = x + ((size_t)am * T_ + t) * F_ + lk;
    #pragma unroll
    for (int kt = 0; kt < 8; ++kt) {
      float4_t xa = *(const float4_t*)(xrow + kt * 32);
      float4_t xb = *(const float4_t*)(xrow + kt * 32 + 4);
      bfrag a;
      #pragma unroll
      for (int e = 0; e < 4; ++e) { a[e] = f2bf(xa[e]); a[4 + e] = f2bf(xb[e]); }
      a0 = __builtin_amdgcn_mfma_f32_16x16x32_bf16(a, BW[0][kt], a0, 0, 0, 0);
      a1 = __builtin_amdgcn_mfma_f32_16x16x32_bf16(a, BW[1][kt], a1, 0, 0, 0);
    }
  };

  f32x4 xp0 = {0.f, 0.f, 0.f, 0.f}, xp1 = {0.f, 0.f, 0.f, 0.f};
  xpart(0, xp0, xp1);

  for (int t = 0; t < T_; ++t) {
    // ---- wait for h_t (all waves poll; relaxed loads, no cache-maint fence) ----
    if (t > 0) {
      int v;
      do {
        v = __hip_atomic_load(&wgdone[l], __ATOMIC_RELAXED, __HIP_MEMORY_SCOPE_AGENT);
        if (__all(v >= t)) break;
        __builtin_amdgcn_s_sleep(1);
      } while (true);
      __builtin_amdgcn_fence(__ATOMIC_ACQUIRE, "workgroup");  // compiler order only
    }

    const __hip_bfloat16* hcur = (t & 1) ? hb1 : hb0;
    __hip_bfloat16*       hnxt = (t & 1) ? hb0 : hb1;

    // ---- h fragments (agent-scope relaxed atomic 8B loads) ----
    bfrag ha[16];
    const unsigned long long* hrow =
        (const unsigned long long*)(hcur + (size_t)am * H_) + (lk >> 2);
    #pragma unroll
    for (int kt = 0; kt < 16; ++kt) {
      unsigned long long u0 = __hip_atomic_load(hrow + kt * 8,     __ATOMIC_RELAXED, __HIP_MEMORY_SCOPE_AGENT);
      unsigned long long u1 = __hip_atomic_load(hrow + kt * 8 + 1, __ATOMIC_RELAXED, __HIP_MEMORY_SCOPE_AGENT);
      short4_t s0 = __builtin_bit_cast(short4_t, u0);
      short4_t s1 = __builtin_bit_cast(short4_t, u1);
      ha[kt] = __builtin_shufflevector(s0, s1, 0, 1, 2, 3, 4, 5, 6, 7);
    }

    // ---- gates: h part (K 256..767) on top of precomputed x part ----
    f32x4 acc0 = xp0, acc1 = xp1;
    #pragma unroll
    for (int kt = 0; kt < 16; ++kt) {
      acc0 = __builtin_amdgcn_mfma_f32_16x16x32_bf16(ha[kt], BW[0][8 + kt], acc0, 0, 0, 0);
      acc1 = __builtin_amdgcn_mfma_f32_16x16x32_bf16(ha[kt], BW[1][8 + kt], acc1, 0, 0, 0);
    }

    // ---- activations, state update, packed h store (4B atomics) ----
    unsigned int* hst32 = (unsigned int*)hnxt;
    #pragma unroll
    for (int r = 0; r < 4; ++r) {
      float fvx = __shfl_xor(acc0[r], 8);   // f gate (n = 8+j) from partner lane
      float ovx = __shfl_xor(acc1[r], 8);   // o gate (n = 24+j)
      float hn = 0.f;
      if (l16 < 8) {
        float iv = fsig(acc0[r] + bs0);
        float fv = fsig(fvx + bs1);
        float gv = ftanh(acc1[r] + bs2);
        float ov = fsig(ovx + bs3);
        float cn = fv * c4[r] + iv * gv;
        c4[r] = cn;
        hn = ov * ftanh(cn);
      }
      int hb16 = (int)(unsigned short)f2bf(hn);
      int pu   = __shfl_xor(hb16, 1);
      if ((l16 < 8) && ((l16 & 1) == 0)) {
        unsigned int packed = ((unsigned)hb16 & 0xffffu) | ((unsigned)pu << 16);
        __hip_atomic_store(&hst32[((size_t)(dmBase + r) * H_ + g * 8 + l16) >> 1],
                           packed, __ATOMIC_RELAXED, __HIP_MEMORY_SCOPE_AGENT);
      }
    }

    __syncthreads();   // drains vmcnt(0): all waves' h stores completed at coherence point
    if (tid == 0)
      __hip_atomic_store(&wgdone[g], t + 1, __ATOMIC_RELAXED, __HIP_MEMORY_SCOPE_AGENT);

    // ---- shadow work (off critical path): out[t-1] GEMM + store, next x part ----
    if (t > 0) {
      f32x4 oacc = {blc, blc, blc, blc};
      #pragma unroll
      for (int kt = 0; kt < 16; ++kt)
        oacc = __builtin_amdgcn_mfma_f32_16x16x32_bf16(ha[kt], BL[kt], oacc, 0, 0, 0);
      if (l16 < 4) {
        #pragma unroll
        for (int r = 0; r < 4; ++r)
          out[(size_t)(dmBase + r) * T_ * F_ + (size_t)(t - 1) * F_ + g * 4 + l16] = oacc[r];
      }
    }
    xp0 = (f32x4){0.f, 0.f, 0.f, 0.f};
    xp1 = (f32x4){0.f, 0.f, 0.f, 0.f};
    if (t + 1 < T_) xpart(t + 1, xp0, xp1);
  }

  // ---- tail: out[:, T-1, :] from h_T (in hb0, since T even) ----
  {
    int v;
    do {
      v = __hip_atomic_load(&wgdone[l], __ATOMIC_RELAXED, __HIP_MEMORY_SCOPE_AGENT);
      if (__all(v >= T_)) break;
      __builtin_amdgcn_s_sleep(1);
    } while (true);
    __builtin_amdgcn_fence(__ATOMIC_ACQUIRE, "workgroup");

    f32x4 oacc = {blc, blc, blc, blc};
    const unsigned long long* hrow =
        (const unsigned long long*)(hb0 + (size_t)am * H_) + (lk >> 2);
    #pragma unroll
    for (int kt = 0; kt < 16; ++kt) {
      unsigned long long u0 = __hip_atomic_load(hrow + kt * 8,     __ATOMIC_RELAXED, __HIP_MEMORY_SCOPE_AGENT);
      unsigned long long u1 = __hip_atomic_load(hrow + kt * 8 + 1, __ATOMIC_RELAXED, __HIP_MEMORY_SCOPE_AGENT);
      short4_t s0 = __builtin_bit_cast(short4_t, u0);
      short4_t s1 = __builtin_bit_cast(short4_t, u1);
      bfrag a = __builtin_shufflevector(s0, s1, 0, 1, 2, 3, 4, 5, 6, 7);
      oacc = __builtin_amdgcn_mfma_f32_16x16x32_bf16(a, BL[kt], oacc, 0, 0, 0);
    }
    if (l16 < 4) {
      #pragma unroll
      for (int r = 0; r < 4; ++r)
        out[(size_t)(dmBase + r) * T_ * F_ + (size_t)(T_ - 1) * F_ + g * 4 + l16] = oacc[r];
    }
  }
}

extern "C" void kernel_launch(void* const* d_in, const int* in_sizes, int n_in,
                              void* d_out, int out_size, void* d_ws, size_t ws_size,
                              hipStream_t stream) {
  const float* z    = (const float*)d_in[0];
  const float* x    = (const float*)d_in[1];
  const float* Wih  = (const float*)d_in[2];
  const float* Whh  = (const float*)d_in[3];
  const float* bih  = (const float*)d_in[4];
  const float* bhh  = (const float*)d_in[5];
  const float* Wlin = (const float*)d_in[6];
  const float* blin = (const float*)d_in[7];
  float* out = (float*)d_out;

  __hip_bfloat16* hb0 = (__hip_bfloat16*)d_ws;
  __hip_bfloat16* hb1 = hb0 + B_ * H_;
  int* wgdone = (int*)((char*)d_ws + (size_t)2 * B_ * H_ * sizeof(__hip_bfloat16));

  lstm_init<<<64, 256, 0, stream>>>(z, hb0, wgdone);
  lstm_persist<<<NWG, 256, 0, stream>>>(x, Wih, Whh, bih, bhh, Wlin, blin, out,
                                        hb0, hb1, wgdone);
}

// Round 3
// 15392.296 us; speedup vs baseline: 1.7220x; 1.2071x over previous
//
#include <hip/hip_runtime.h>
#include <hip/hip_bf16.h>

#define B_   64
#define T_   2048
#define F_   256
#define H_   512
#define NWG  64

typedef __attribute__((ext_vector_type(8))) short bfrag;   // 8 bf16 = 4 VGPR (MFMA A/B operand)
typedef __attribute__((ext_vector_type(4))) int   int4v;   // 16B load payload
typedef __attribute__((ext_vector_type(4))) float f32x4;   // MFMA C/D
typedef __attribute__((ext_vector_type(4))) float float4_t;

__device__ __forceinline__ float fsig(float x)  { return 1.0f / (1.0f + __expf(-x)); }
__device__ __forceinline__ float ftanh(float x) { return 2.0f / (1.0f + __expf(-2.0f * x)) - 1.0f; }

__device__ __forceinline__ short f2bf(float f) {
  __hip_bfloat16 h = __float2bfloat16(f);
  return __builtin_bit_cast(short, h);
}

// ---- coherence-point (device-scope, L1+L2-bypass) memory ops via inline asm.
// sc0 sc1 = bypass CU L1 and XCD L2 -> serviced at the coherent MALL/L3.
// Issued as plain VMEM ops -> pipeline under vmcnt (the whole point: the HIP
// compiler serializes __hip_atomic_load one-per-roundtrip; these don't).
__device__ __forceinline__ int4v gload16_cc(const void* p) {
  int4v r;
  asm volatile("global_load_dwordx4 %0, %1, off sc0 sc1" : "=v"(r) : "v"(p));
  return r;
}
__device__ __forceinline__ int gload_flag(const void* p) {
  int r;  // load + in-asm drain: r is architecturally valid on asm exit
  asm volatile("global_load_dword %0, %1, off sc0 sc1\n\ts_waitcnt vmcnt(0)"
               : "=v"(r) : "v"(p) : "memory");
  return r;
}
__device__ __forceinline__ void gstore4_cc(void* p, unsigned int d) {
  asm volatile("global_store_dword %0, %1, off sc0 sc1" :: "v"(p), "v"(d));
}
__device__ __forceinline__ void vm_drain() {
  asm volatile("s_waitcnt vmcnt(0)" ::: "memory");
  __builtin_amdgcn_sched_barrier(0);   // rule #18: block hoisting past the wait
}

// ---------------- init: zero flags, h0 = bf16(z) ----------------
// (plain stores: end-of-kernel implicit release writes back L2 -> visible to
//  the persist kernel's uncached reads)
__global__ void lstm_init(const float* __restrict__ z, __hip_bfloat16* __restrict__ hb0,
                          int* __restrict__ wgdone) {
  int i = blockIdx.x * blockDim.x + threadIdx.x;
  if (i < NWG) wgdone[i] = 0;
  for (int idx = i; idx < B_ * H_; idx += gridDim.x * blockDim.x)
    hb0[idx] = __float2bfloat16(z[idx]);
}

// ---------------- persistent LSTM ----------------
// WG g owns: gate rows {q*512 + g*8 + j : q=0..3, j=0..7}  -> h cols [g*8, g*8+8)
//            out cols  [g*4, g*4+4)
// Wave w handles batch rows [16w, 16w+16).
// Sync: h + flags ONLY via sc0sc1 (coherence-point) asm ops. vm_drain before
// __syncthreads guarantees h stores completed before the flag store issues.
__global__ void __launch_bounds__(256, 1)
lstm_persist(const float* __restrict__ x,
             const float* __restrict__ Wih,  const float* __restrict__ Whh,
             const float* __restrict__ bih,  const float* __restrict__ bhh,
             const float* __restrict__ Wlin, const float* __restrict__ blin,
             float* __restrict__ out,
             __hip_bfloat16* __restrict__ hb0, __hip_bfloat16* __restrict__ hb1,
             int* __restrict__ wgdone)
{
  const int g   = blockIdx.x;        // 0..63
  const int tid = threadIdx.x;
  const int wv  = tid >> 6;          // wave 0..3
  const int l   = tid & 63;
  const int l16 = l & 15;
  const int lk  = (l >> 4) << 3;     // k sub-offset: 0,8,16,24

  // ---- persistent weight fragments in VGPRs/AGPRs (bf16) ----
  bfrag BW[2][24];   // [n-tile][k-tile]; k 0..7 = W_ih (K 0..255), 8..23 = W_hh
  #pragma unroll
  for (int nt = 0; nt < 2; ++nt) {
    const int n   = nt * 16 + l16;
    const int row = (n >> 3) * H_ + g * 8 + (n & 7);   // gate row
    #pragma unroll
    for (int kt = 0; kt < 24; ++kt) {
      const float* src = (kt < 8) ? (Wih + (size_t)row * F_ + kt * 32 + lk)
                                  : (Whh + (size_t)row * H_ + (kt - 8) * 32 + lk);
      bfrag w;
      #pragma unroll
      for (int e = 0; e < 8; ++e) w[e] = f2bf(src[e]);
      BW[nt][kt] = w;
    }
  }
  bfrag BL[16];      // W_lin fragments (cols g*4 .. g*4+3 valid; others zeroed)
  {
    const bool v  = (l16 < 4);
    const int col = g * 4 + (l16 & 3);
    #pragma unroll
    for (int kt = 0; kt < 16; ++kt) {
      bfrag w;
      #pragma unroll
      for (int e = 0; e < 8; ++e)
        w[e] = v ? f2bf(Wlin[(size_t)col * H_ + kt * 32 + lk + e]) : (short)0;
      BL[kt] = w;
    }
  }
  float bs0 = 0.f, bs1 = 0.f, bs2 = 0.f, bs3 = 0.f, blc = 0.f;
  if (l16 < 8) {
    const int c0 = g * 8 + l16;
    bs0 = bih[c0]          + bhh[c0];           // i
    bs1 = bih[H_ + c0]     + bhh[H_ + c0];      // f
    bs2 = bih[2 * H_ + c0] + bhh[2 * H_ + c0];  // g
    bs3 = bih[3 * H_ + c0] + bhh[3 * H_ + c0];  // o
  }
  if (l16 < 4) blc = blin[g * 4 + l16];

  float c4[4] = {0.f, 0.f, 0.f, 0.f};           // cell state, rows dmBase+r

  const int am     = wv * 16 + l16;              // A-operand batch row
  const int dmBase = wv * 16 + ((l >> 4) << 2);  // D row base (+reg)

  // x-part of the gates GEMM for step t (h-independent; runs in shadow phase)
  auto xpart = [&](int t, f32x4& a0, f32x4& a1) {
    const float* xrow = x + ((size_t)am * T_ + t) * F_ + lk;
    #pragma unroll
    for (int kt = 0; kt < 8; ++kt) {
      float4_t xa = *(const float4_t*)(xrow + kt * 32);
      float4_t xb = *(const float4_t*)(xrow + kt * 32 + 4);
      bfrag a;
      #pragma unroll
      for (int e = 0; e < 4; ++e) { a[e] = f2bf(xa[e]); a[4 + e] = f2bf(xb[e]); }
      a0 = __builtin_amdgcn_mfma_f32_16x16x32_bf16(a, BW[0][kt], a0, 0, 0, 0);
      a1 = __builtin_amdgcn_mfma_f32_16x16x32_bf16(a, BW[1][kt], a1, 0, 0, 0);
    }
  };

  f32x4 xp0 = {0.f, 0.f, 0.f, 0.f}, xp1 = {0.f, 0.f, 0.f, 0.f};
  xpart(0, xp0, xp1);

  for (int t = 0; t < T_; ++t) {
    // ---- wait for h_t (all waves poll; pipelined uncached flag loads) ----
    if (t > 0) {
      while (true) {
        int v = gload_flag(&wgdone[l]);
        if (__all(v >= t)) break;
        __builtin_amdgcn_s_sleep(1);
      }
      __builtin_amdgcn_sched_barrier(0);
    }

    const __hip_bfloat16* hcur = (t & 1) ? hb1 : hb0;
    __hip_bfloat16*       hnxt = (t & 1) ? hb0 : hb1;

    // ---- h fragments: 16 x 16B coherence-point loads, ALL in flight, one drain ----
    int4v hv[16];
    const char* hbase = (const char*)hcur + ((size_t)am * H_ + lk) * 2;
    #pragma unroll
    for (int kt = 0; kt < 16; ++kt)
      hv[kt] = gload16_cc(hbase + (size_t)kt * 64);   // 32 cols * 2B = 64B stride
    vm_drain();

    // ---- gates: h part (K 256..767) on top of precomputed x part ----
    f32x4 acc0 = xp0, acc1 = xp1;
    #pragma unroll
    for (int kt = 0; kt < 16; ++kt) {
      bfrag ha = __builtin_bit_cast(bfrag, hv[kt]);
      acc0 = __builtin_amdgcn_mfma_f32_16x16x32_bf16(ha, BW[0][8 + kt], acc0, 0, 0, 0);
      acc1 = __builtin_amdgcn_mfma_f32_16x16x32_bf16(ha, BW[1][8 + kt], acc1, 0, 0, 0);
    }

    // ---- activations, state update, packed h store (4B uncached stores) ----
    unsigned int* hst32 = (unsigned int*)hnxt;
    #pragma unroll
    for (int r = 0; r < 4; ++r) {
      float fvx = __shfl_xor(acc0[r], 8);   // f gate (n = 8+j) from partner lane
      float ovx = __shfl_xor(acc1[r], 8);   // o gate (n = 24+j)
      float hn = 0.f;
      if (l16 < 8) {
        float iv = fsig(acc0[r] + bs0);
        float fv = fsig(fvx + bs1);
        float gv = ftanh(acc1[r] + bs2);
        float ov = fsig(ovx + bs3);
        float cn = fv * c4[r] + iv * gv;
        c4[r] = cn;
        hn = ov * ftanh(cn);
      }
      int hb16 = (int)(unsigned short)f2bf(hn);
      int pu   = __shfl_xor(hb16, 1);
      if ((l16 < 8) && ((l16 & 1) == 0)) {
        unsigned int packed = ((unsigned)hb16 & 0xffffu) | ((unsigned)pu << 16);
        gstore4_cc(&hst32[((size_t)(dmBase + r) * H_ + g * 8 + l16) >> 1], packed);
      }
    }

    vm_drain();        // h stores completed at coherence point
    __syncthreads();   // all 4 waves' stores done
    if (tid == 0)
      gstore4_cc(&wgdone[g], (unsigned int)(t + 1));

    // ---- shadow work (off critical path): out[t-1] GEMM + store, next x part ----
    if (t > 0) {
      f32x4 oacc = {blc, blc, blc, blc};
      #pragma unroll
      for (int kt = 0; kt < 16; ++kt) {
        bfrag ha = __builtin_bit_cast(bfrag, hv[kt]);
        oacc = __builtin_amdgcn_mfma_f32_16x16x32_bf16(ha, BL[kt], oacc, 0, 0, 0);
      }
      if (l16 < 4) {
        #pragma unroll
        for (int r = 0; r < 4; ++r)
          out[(size_t)(dmBase + r) * T_ * F_ + (size_t)(t - 1) * F_ + g * 4 + l16] = oacc[r];
      }
    }
    xp0 = (f32x4){0.f, 0.f, 0.f, 0.f};
    xp1 = (f32x4){0.f, 0.f, 0.f, 0.f};
    if (t + 1 < T_) xpart(t + 1, xp0, xp1);
  }

  // ---- tail: out[:, T-1, :] from h_T (in hb0, since T even) ----
  {
    while (true) {
      int v = gload_flag(&wgdone[l]);
      if (__all(v >= T_)) break;
      __builtin_amdgcn_s_sleep(1);
    }
    __builtin_amdgcn_sched_barrier(0);

    int4v hv[16];
    const char* hbase = (const char*)hb0 + ((size_t)am * H_ + lk) * 2;
    #pragma unroll
    for (int kt = 0; kt < 16; ++kt)
      hv[kt] = gload16_cc(hbase + (size_t)kt * 64);
    vm_drain();

    f32x4 oacc = {blc, blc, blc, blc};
    #pragma unroll
    for (int kt = 0; kt < 16; ++kt) {
      bfrag ha = __builtin_bit_cast(bfrag, hv[kt]);
      oacc = __builtin_amdgcn_mfma_f32_16x16x32_bf16(ha, BL[kt], oacc, 0, 0, 0);
    }
    if (l16 < 4) {
      #pragma unroll
      for (int r = 0; r < 4; ++r)
        out[(size_t)(dmBase + r) * T_ * F_ + (size_t)(T_ - 1) * F_ + g * 4 + l16] = oacc[r];
    }
  }
}

extern "C" void kernel_launch(void* const* d_in, const int* in_sizes, int n_in,
                              void* d_out, int out_size, void* d_ws, size_t ws_size,
                              hipStream_t stream) {
  const float* z    = (const float*)d_in[0];
  const float* x    = (const float*)d_in[1];
  const float* Wih  = (const float*)d_in[2];
  const float* Whh  = (const float*)d_in[3];
  const float* bih  = (const float*)d_in[4];
  const float* bhh  = (const float*)d_in[5];
  const float* Wlin = (const float*)d_in[6];
  const float* blin = (const float*)d_in[7];
  float* out = (float*)d_out;

  __hip_bfloat16* hb0 = (__hip_bfloat16*)d_ws;
  __hip_bfloat16* hb1 = hb0 + B_ * H_;
  int* wgdone = (int*)((char*)d_ws + (size_t)2 * B_ * H_ * sizeof(__hip_bfloat16));

  lstm_init<<<64, 256, 0, stream>>>(z, hb0, wgdone);
  lstm_persist<<<NWG, 256, 0, stream>>>(x, Wih, Whh, bih, bhh, Wlin, blin, out,
                                        hb0, hb1, wgdone);
}